// Round 1
// baseline (197.503 us; speedup 1.0000x reference)
//
#include <hip/hip_runtime.h>
#include <stdint.h>

typedef __bf16 bf16x8 __attribute__((ext_vector_type(8)));
typedef float floatx4 __attribute__((ext_vector_type(4)));
typedef uint32_t uint32x4 __attribute__((ext_vector_type(4)));

#define GRID_W   15
#define PAD_W    17
#define CELLS    221            // 13*17 padded cells
#define HEXDIM   64
#define NHEX     165
#define OUTC     64
#define KDIM     448
#define CWORDS   32             // uint32 words per cell (64 bf16)
#define SXWORDS  (CELLS * CWORDS)   // 7072 words = 28288 B

// round-to-nearest-even fp32 -> bf16, packed pair
__device__ __forceinline__ uint32_t pack2bf(float a, float b) {
    union { float f; uint32_t u; } ua, ub;
    ua.f = a; ub.f = b;
    uint32_t ra = (ua.u + 0x7fffu + ((ua.u >> 16) & 1u)) >> 16;
    uint32_t rb = (ub.u + 0x7fffu + ((ub.u >> 16) & 1u)) >> 16;
    return ra | (rb << 16);
}

// ---- prep: W fp32 -> bf16 (64*448 = 28672 elems, 7168 float4s, 28 blocks) ----
__global__ void wprep_kernel(const float* __restrict__ W, uint32_t* __restrict__ Wbf) {
    int i = blockIdx.x * 256 + threadIdx.x;   // float4 index
    float4 v = ((const float4*)W)[i];
    uint2 p; p.x = pack2bf(v.x, v.y); p.y = pack2bf(v.z, v.w);
    ((uint2*)Wbf)[i] = p;
}

// Operand-swapped MFMA: A = W fragment (o rows), B = x fragment (hex cols).
// A and B lane layouts are identical (non-k = lane&15, k-chunk = lane>>4), so
// the same register data serves either slot; swapping transposes the C tile to
// (o = row, hex = col) -> each lane holds 4 consecutive o's for one hex.
__device__ __forceinline__ floatx4 mfma16(uint32x4 a, uint32x4 b, floatx4 c) {
    return __builtin_amdgcn_mfma_f32_16x16x32_bf16(
        __builtin_bit_cast(bf16x8, a), __builtin_bit_cast(bf16x8, b), c, 0, 0, 0);
}

__global__ __launch_bounds__(512, 4)
void hexconv_kernel(const float* __restrict__ x,
                    const uint32_t* __restrict__ Wbf,
                    const float* __restrict__ bias,
                    float* __restrict__ out)
{
    __shared__ __align__(16) uint32_t sx[SXWORDS];   // 28,288 B — only LDS; 4 blocks/CU

    const int tid  = threadIdx.x;
    const int b    = blockIdx.x;
    const int wave = tid >> 6;
    const int lane = tid & 63;
    const int col  = lane & 15;   // o within tile (A-row) / hex within tile (B-col/C-col)
    const int kq   = lane >> 4;   // k-quad
    const int og   = wave & 1;    // o-pair: o-tiles og*2, og*2+1
    const int mg   = wave >> 1;   // m-group: m-tiles mg*3 + {0,1,2}  (12 m-tiles total)

    const uint32_t* w0 = Wbf + (og * 32 +      col) * (KDIM / 2) + kq * 4;
    const uint32_t* w1 = Wbf + (og * 32 + 16 + col) * (KDIM / 2) + kq * 4;

    // ---- K-half 0 W fragments: issue BEFORE staging so they fly under the x loads ----
    uint32x4 wf[2][7];
    #pragma unroll
    for (int ksl = 0; ksl < 7; ++ksl) {
        wf[0][ksl] = *(const uint32x4*)(w0 + ksl * 16);
        wf[1][ksl] = *(const uint32x4*)(w1 + ksl * 16);
    }

    // ---- stage interior (fp32 -> bf16, swizzled) + zero the 56 halo cells; ONE barrier ----
    {
        const float4* xs = (const float4*)(x + (size_t)b * NHEX * HEXDIM);
        for (int i = tid; i < NHEX * HEXDIM / 4; i += 512) {
            int n = i >> 4;            // hex index
            int d = i & 15;            // float4 within hex
            float4 v = xs[i];
            int y0 = n / GRID_W, x0 = n - y0 * GRID_W;
            int cell = (y0 + 1) * PAD_W + (x0 + 1);
            int pc   = (d >> 1) ^ (cell & 7);               // swizzled 16B chunk
            uint32_t* dst = sx + cell * CWORDS + pc * 4 + (d & 1) * 2;
            uint2 p; p.x = pack2bf(v.x, v.y); p.y = pack2bf(v.z, v.w);
            *(uint2*)dst = p;
        }
        // halo = 56 cells x 8 chunks of 16B (disjoint from interior -> same phase)
        for (int i = tid; i < 56 * 8; i += 512) {
            int c = i >> 3, ch = i & 7;
            int cell;
            if (c < 17)      cell = c;                        // top row 0
            else if (c < 34) cell = 12 * PAD_W + (c - 17);    // bottom row 12
            else if (c < 45) cell = (c - 33) * PAD_W;         // left col, rows 1..11
            else             cell = (c - 44) * PAD_W + 16;    // right col, rows 1..11
            uint32x4 z = {0u, 0u, 0u, 0u};
            *(uint32x4*)(sx + cell * CWORDS + ch * 4) = z;
        }
    }
    __syncthreads();

    const int off0[7] = {-17, -16, -1, 0, 1, 17, 18};
    const int off1[7] = {-18, -17, -1, 0, 1, 16, 17};

    floatx4 acc[3][2];
    #pragma unroll
    for (int m = 0; m < 3; ++m) {
        acc[m][0] = (floatx4){0.f, 0.f, 0.f, 0.f};
        acc[m][1] = (floatx4){0.f, 0.f, 0.f, 0.f};
    }

    // ---- main loop: full-K per wave, K in two halves (W frags reloaded from L2) ----
    #pragma unroll
    for (int half = 0; half < 2; ++half) {
        if (half == 1) {
            #pragma unroll
            for (int ksl = 0; ksl < 7; ++ksl) {
                wf[0][ksl] = *(const uint32x4*)(w0 + 112 + ksl * 16);
                wf[1][ksl] = *(const uint32x4*)(w1 + 112 + ksl * 16);
            }
        }
        #pragma unroll
        for (int mt3 = 0; mt3 < 3; ++mt3) {
            const int mt = mg * 3 + mt3;
            int n = mt * 16 + col;
            bool valid = (n < NHEX);
            int nn = valid ? n : 0;
            int y0 = nn / GRID_W, x0 = nn - y0 * GRID_W;
            int base = (y0 + 1) * PAD_W + (x0 + 1);
            bool use0 = (y0 & 1);
            #pragma unroll
            for (int ksl = 0; ksl < 7; ++ksl) {
                const int ks = half * 7 + ksl;   // constexpr after unroll
                const int j  = ks >> 1;          // neighbor 0..6
                const int h  = ks & 1;           // dim-half of neighbor
                int c  = valid ? (base + (use0 ? off0[j] : off1[j])) : 16; // cell 16 = halo(0)
                int ch = ((h * 4 + kq) ^ (c & 7));
                uint32x4 bv = *(const uint32x4*)(sx + c * CWORDS + ch * 4); // ds_read_b128
                acc[mt3][0] = mfma16(wf[0][ksl], bv, acc[mt3][0]);
                acc[mt3][1] = mfma16(wf[1][ksl], bv, acc[mt3][1]);
            }
        }
    }

    // ---- epilogue: lane holds 4 consecutive o's for one hex -> float4 stores ----
    float4 b40 = *(const float4*)(bias + og * 32 + kq * 4);
    float4 b41 = *(const float4*)(bias + og * 32 + 16 + kq * 4);
    float* outb = out + (size_t)b * NHEX * OUTC;
    #pragma unroll
    for (int mt3 = 0; mt3 < 3; ++mt3) {
        int n = (mg * 3 + mt3) * 16 + col;
        if (n < NHEX) {
            float* po = outb + (size_t)n * OUTC + og * 32 + kq * 4;
            float4 v0, v1;
            v0.x = acc[mt3][0][0] + b40.x; v0.y = acc[mt3][0][1] + b40.y;
            v0.z = acc[mt3][0][2] + b40.z; v0.w = acc[mt3][0][3] + b40.w;
            v1.x = acc[mt3][1][0] + b41.x; v1.y = acc[mt3][1][1] + b41.y;
            v1.z = acc[mt3][1][2] + b41.z; v1.w = acc[mt3][1][3] + b41.w;
            *(float4*)po        = v0;   // o = og*32 + kq*4 .. +3
            *(float4*)(po + 16) = v1;   // o = og*32 + 16 + kq*4 .. +3
        }
    }
}

extern "C" void kernel_launch(void* const* d_in, const int* in_sizes, int n_in,
                              void* d_out, int out_size, void* d_ws, size_t ws_size,
                              hipStream_t stream) {
    const float* x    = (const float*)d_in[0];
    const float* W    = (const float*)d_in[1];
    const float* bias = (const float*)d_in[2];
    float* out        = (float*)d_out;
    uint32_t* Wbf     = (uint32_t*)d_ws;      // 57,344 B of bf16 W

    wprep_kernel<<<28, 256, 0, stream>>>(W, Wbf);

    int B = in_sizes[0] / (NHEX * HEXDIM);
    hexconv_kernel<<<B, 512, 0, stream>>>(x, Wbf, bias, out);
}